// Round 1
// baseline (188.216 us; speedup 1.0000x reference)
//
#include <hip/hip_runtime.h>
#include <hip/hip_bf16.h>

#define N_NODES 65536
#define D_FEAT  64
#define N_EDGES 1048576
#define NBUCK   512          // buckets per matrix; bucket = row >> 7
#define ROWS_PB 128
#define BCAP    2560         // mean 2048, +11 sigma headroom
#define EPB     8192         // edges per bin block
#define XH_ELEMS ((size_t)N_NODES * D_FEAT)   // 4,194,304 elems per matrix

// ---------------- bf16 helpers (round-to-nearest-even) ----------------
static __device__ __forceinline__ unsigned short f2bf(float f) {
    unsigned b = __float_as_uint(f);
    return (unsigned short)((b + 0x7fffu + ((b >> 16) & 1u)) >> 16);
}

// Wave64 inclusive scan via shfl_up (no barriers inside a wave).
static __device__ __forceinline__ int wave_incl_scan(int v, int lane) {
    #pragma unroll
    for (int d = 1; d < 64; d <<= 1) {
        int t = __shfl_up(v, d, 64);
        if (lane >= d) v += t;
    }
    return v;
}

// ---------------- bin (+ fused fp32->bf16 cvt): LDS counting sort -------
// 256 blocks (128/matrix) x 1024 threads x 8 edges. Each block also
// converts 8192 float4s of x1/x2 to bf16 (replaces the old cvt_kernel).
// Scan over 512 bins is shfl-based: 2 barriers instead of 18.
__global__ __launch_bounds__(1024) void bin_kernel(
    const float* __restrict__ x1, const float* __restrict__ x2,
    unsigned short* __restrict__ xh,
    const int* __restrict__ r1, const int* __restrict__ c1, const float* __restrict__ v1,
    const int* __restrict__ r2, const int* __restrict__ c2, const float* __restrict__ v2,
    int*   __restrict__ gcursor,       // [2*NBUCK], zeroed
    uint2* __restrict__ perm)          // [2*NBUCK*BCAP]
{
    __shared__ uint2 ent[EPB];                 // 64 KB
    __shared__ unsigned short binof[EPB];      // 16 KB
    __shared__ int hist[NBUCK];
    __shared__ int offs[NBUCK];
    __shared__ int cur[NBUCK];
    __shared__ int gbase[NBUCK];
    __shared__ int wsum[8];

    const int tid  = threadIdx.x;
    const int lane = tid & 63;
    const int wv   = tid >> 6;
    const int mat  = blockIdx.x >> 7;          // 128 blocks per matrix
    const int lb   = blockIdx.x & 127;
    const int*   rows = mat ? r2 : r1;
    const int*   cols = mat ? c2 : c1;
    const float* vals = mat ? v2 : v1;
    uint2* pm = perm + (size_t)mat * NBUCK * BCAP;

    for (int i = tid; i < NBUCK; i += 1024) hist[i] = 0;

    // Issue edge loads early; their latency hides under the cvt work.
    const int base_e = lb * EPB;
    int r[8], c[8];
    float v[8];
    *(int4*)&r[0]   = ((const int4*)(rows + base_e))[tid * 2];
    *(int4*)&r[4]   = ((const int4*)(rows + base_e))[tid * 2 + 1];
    *(int4*)&c[0]   = ((const int4*)(cols + base_e))[tid * 2];
    *(int4*)&c[4]   = ((const int4*)(cols + base_e))[tid * 2 + 1];
    *(float4*)&v[0] = ((const float4*)(vals + base_e))[tid * 2];
    *(float4*)&v[4] = ((const float4*)(vals + base_e))[tid * 2 + 1];

    // Fused cvt: 256 blocks x 8192 float4 = 2,097,152 float4 (both matrices).
    {
        const size_t half  = XH_ELEMS / 4;                 // float4s per matrix
        const size_t cbase = (size_t)blockIdx.x * 8192;
        #pragma unroll
        for (int k = 0; k < 8; ++k) {
            size_t i = cbase + (size_t)k * 1024 + tid;
            float4 f = (i < half) ? ((const float4*)x1)[i]
                                  : ((const float4*)x2)[i - half];
            ushort4 o;
            o.x = f2bf(f.x); o.y = f2bf(f.y); o.z = f2bf(f.z); o.w = f2bf(f.w);
            ((ushort4*)xh)[i] = o;
        }
    }

    __syncthreads();
    #pragma unroll
    for (int k = 0; k < 8; ++k) atomicAdd(&hist[r[k] >> 7], 1);
    __syncthreads();

    // Shfl-based exclusive scan over 512 bins (waves 0..7).
    int my = 0, incl = 0;
    if (wv < 8) {
        my   = hist[tid];
        incl = wave_incl_scan(my, lane);
        if (lane == 63) wsum[wv] = incl;
    }
    __syncthreads();
    if (wv < 8) {
        int add = 0;
        #pragma unroll
        for (int w = 0; w < 8; ++w) if (w < wv) add += wsum[w];
        const int excl = incl - my + add;
        offs[tid] = excl;
        cur[tid]  = excl;
        gbase[tid] = atomicAdd(&gcursor[mat * NBUCK + tid], my);   // reserve run
    }
    __syncthreads();

    // Scatter into LDS sorted-by-bucket order.
    #pragma unroll
    for (int k = 0; k < 8; ++k) {
        const int b = r[k] >> 7;
        const int pos = atomicAdd(&cur[b], 1);
        uint2 e;
        e.x = __float_as_uint(v[k]);
        e.y = ((unsigned)c[k] << 7) | ((unsigned)r[k] & 127u);
        ent[pos]   = e;
        binof[pos] = (unsigned short)b;
    }
    __syncthreads();

    // Burst write: consecutive i -> consecutive perm addresses within a run.
    for (int i = tid; i < EPB; i += 1024) {
        const int b   = binof[i];
        const int idx = gbase[b] + (i - offs[b]);
        if (idx < BCAP) pm[(size_t)b * BCAP + idx] = ent[i];
    }
}

// ---------------- fused in-LDS sort + CSR SpMM ----------------
// New gather geometry: 8 lanes/edge, uint4 (16B/lane) loads of 8 bf16 feats.
// Dual-row interleave: each wave processes rows (r, r+1) with independent
// accumulator banks so gathers from two rows stay in flight across row
// boundaries. launch_bounds(1024,8) pins VGPR<=64 for 32 waves/CU.
__global__ __launch_bounds__(1024, 8) void spmm_kernel(
    const int*            __restrict__ gcursor,
    const uint2*          __restrict__ perm,
    const unsigned short* __restrict__ xh,
    float*                __restrict__ out)
{
    __shared__ uint2 ent[BCAP];            // 20 KB
    __shared__ int   hist[ROWS_PB];
    __shared__ int   offs[ROWS_PB + 1];
    __shared__ int   cur[ROWS_PB];
    __shared__ int   wscr[2];

    const int gb   = blockIdx.x;
    const int mat  = gb >> 9;
    const int b    = gb & 511;
    const int tid  = threadIdx.x;
    const int lane = tid & 63;
    const int wave = tid >> 6;

    const uint2* pbase = perm + ((size_t)mat * NBUCK + b) * BCAP;
    const unsigned short* xm = xh + (size_t)mat * XH_ELEMS;
    float* ob = out + (size_t)mat * XH_ELEMS + (size_t)b * ROWS_PB * D_FEAT;

    const int cnt = min(gcursor[mat * NBUCK + b], BCAP);

    if (tid < ROWS_PB) hist[tid] = 0;
    __syncthreads();

    uint2 mine[3];
    int nm = 0;
    for (int i = tid; i < cnt; i += 1024) {
        uint2 e = pbase[i];
        mine[nm++] = e;
        atomicAdd(&hist[e.y & (ROWS_PB - 1)], 1);
    }
    __syncthreads();

    // Shfl-based exclusive scan over 128 row-bins (waves 0..1).
    int my = 0, incl = 0;
    if (wave < 2) {
        my   = hist[tid];
        incl = wave_incl_scan(my, lane);
        if (lane == 63) wscr[wave] = incl;
    }
    __syncthreads();
    if (wave < 2) {
        const int excl = incl - my + (wave == 1 ? wscr[0] : 0);
        offs[tid] = excl;
        cur[tid]  = excl;
    }
    if (tid == 0) offs[ROWS_PB] = cnt;
    __syncthreads();

    for (int k = 0; k < nm; ++k) {
        int rr  = mine[k].y & (ROWS_PB - 1);
        int pos = atomicAdd(&cur[rr], 1);
        ent[pos] = mine[k];
    }
    __syncthreads();

    const int sub = lane >> 3;        // which of 8 edges in the group
    const int fl  = lane & 7;         // feature octet index

#define GB(ACC, EE) {                                                        \
        uint2 en = ent[(EE) + sub];                                          \
        float vv = __uint_as_float(en.x);                                    \
        const uint4 q = *(const uint4*)(xm + (((size_t)(en.y >> 7)) << 6)    \
                                           + (fl << 3));                     \
        ACC[0] = fmaf(vv, __uint_as_float(q.x << 16),         ACC[0]);       \
        ACC[1] = fmaf(vv, __uint_as_float(q.x & 0xffff0000u), ACC[1]);       \
        ACC[2] = fmaf(vv, __uint_as_float(q.y << 16),         ACC[2]);       \
        ACC[3] = fmaf(vv, __uint_as_float(q.y & 0xffff0000u), ACC[3]);       \
        ACC[4] = fmaf(vv, __uint_as_float(q.z << 16),         ACC[4]);       \
        ACC[5] = fmaf(vv, __uint_as_float(q.z & 0xffff0000u), ACC[5]);       \
        ACC[6] = fmaf(vv, __uint_as_float(q.w << 16),         ACC[6]);       \
        ACC[7] = fmaf(vv, __uint_as_float(q.w & 0xffff0000u), ACC[7]); }

#define GBM(ACC, EE, END) {                                                  \
        const int idx = (EE) + sub;                                          \
        const bool ok = idx < (END);                                         \
        uint2 en = ent[ok ? idx : (END) - 1];                                \
        float vv = ok ? __uint_as_float(en.x) : 0.f;                         \
        const uint4 q = *(const uint4*)(xm + (((size_t)(en.y >> 7)) << 6)    \
                                           + (fl << 3));                     \
        ACC[0] = fmaf(vv, __uint_as_float(q.x << 16),         ACC[0]);       \
        ACC[1] = fmaf(vv, __uint_as_float(q.x & 0xffff0000u), ACC[1]);       \
        ACC[2] = fmaf(vv, __uint_as_float(q.y << 16),         ACC[2]);       \
        ACC[3] = fmaf(vv, __uint_as_float(q.y & 0xffff0000u), ACC[3]);       \
        ACC[4] = fmaf(vv, __uint_as_float(q.z << 16),         ACC[4]);       \
        ACC[5] = fmaf(vv, __uint_as_float(q.z & 0xffff0000u), ACC[5]);       \
        ACC[6] = fmaf(vv, __uint_as_float(q.w << 16),         ACC[6]);       \
        ACC[7] = fmaf(vv, __uint_as_float(q.w & 0xffff0000u), ACC[7]); }

    #pragma unroll
    for (int rp = 0; rp < 8; rp += 2) {
        const int rA = wave * 8 + rp;
        const int rB = rA + 1;
        int eA = offs[rA]; const int endA = offs[rA + 1];
        int eB = endA;     const int endB = offs[rB + 1];

        float a[8]  = {0.f, 0.f, 0.f, 0.f, 0.f, 0.f, 0.f, 0.f};
        float bq[8] = {0.f, 0.f, 0.f, 0.f, 0.f, 0.f, 0.f, 0.f};

        // Interleaved: loads from two independent rows in flight.
        while (eA + 8 <= endA && eB + 8 <= endB) {
            GB(a, eA) GB(bq, eB)
            eA += 8; eB += 8;
        }
        while (eA + 8 <= endA) { GB(a, eA)  eA += 8; }
        while (eB + 8 <= endB) { GB(bq, eB) eB += 8; }
        if (eA < endA) GBM(a, eA, endA)
        if (eB < endB) GBM(bq, eB, endB)

        #pragma unroll
        for (int i = 0; i < 8; ++i) {
            a[i]  += __shfl_xor(a[i],  8);
            a[i]  += __shfl_xor(a[i],  16);
            a[i]  += __shfl_xor(a[i],  32);
            bq[i] += __shfl_xor(bq[i], 8);
            bq[i] += __shfl_xor(bq[i], 16);
            bq[i] += __shfl_xor(bq[i], 32);
        }

        if (lane < 8) {
            *(float4*)(ob + rA * D_FEAT + (fl << 3))     = make_float4(a[0], a[1], a[2], a[3]);
            *(float4*)(ob + rA * D_FEAT + (fl << 3) + 4) = make_float4(a[4], a[5], a[6], a[7]);
            *(float4*)(ob + rB * D_FEAT + (fl << 3))     = make_float4(bq[0], bq[1], bq[2], bq[3]);
            *(float4*)(ob + rB * D_FEAT + (fl << 3) + 4) = make_float4(bq[4], bq[5], bq[6], bq[7]);
        }
    }
#undef GB
#undef GBM
}

// ---------------- Bottom fallback: atomic kernel ----------------
__global__ __launch_bounds__(256) void spmm_atomic_kernel(
    const float* __restrict__ x,
    const int*   __restrict__ rows,
    const int*   __restrict__ cols,
    const float* __restrict__ vals,
    float*       __restrict__ out,
    int n_edges)
{
    const int gid  = blockIdx.x * blockDim.x + threadIdx.x;
    const int edge = gid >> 6;
    const int lane = threadIdx.x & 63;
    if (edge >= n_edges) return;
    const int   r = rows[edge];
    const int   c = cols[edge];
    const float v = vals[edge];
    atomicAdd(&out[(size_t)r * D_FEAT + lane], v * x[(size_t)c * D_FEAT + lane]);
}

extern "C" void kernel_launch(void* const* d_in, const int* in_sizes, int n_in,
                              void* d_out, int out_size, void* d_ws, size_t ws_size,
                              hipStream_t stream) {
    const float* x1      = (const float*)d_in[0];
    const float* x2      = (const float*)d_in[1];
    const int*   a1_rows = (const int*)  d_in[2];
    const int*   a1_cols = (const int*)  d_in[3];
    const float* a1_vals = (const float*)d_in[4];
    const int*   a2_rows = (const int*)  d_in[5];
    const int*   a2_cols = (const int*)  d_in[6];
    const float* a2_vals = (const float*)d_in[7];

    float* out  = (float*)d_out;
    float* out1 = out;
    float* out2 = out + XH_ELEMS;

    // Workspace: gcursor[1024] | perm[1024*BCAP] | xh[2*XH_ELEMS] bf16
    int*   gcur = (int*)d_ws;
    uint2* perm = (uint2*)(gcur + 2 * NBUCK);
    unsigned short* xh = (unsigned short*)(perm + (size_t)2 * NBUCK * BCAP);

    const size_t needed = 2 * NBUCK * sizeof(int)
                        + (size_t)2 * NBUCK * BCAP * sizeof(uint2)
                        + (size_t)2 * XH_ELEMS * sizeof(short);    // ~37.8 MB

    if (ws_size < needed) {
        hipMemsetAsync(d_out, 0, (size_t)out_size * sizeof(float), stream);
        const int blocks = (N_EDGES * 64 + 255) / 256;
        spmm_atomic_kernel<<<blocks, 256, 0, stream>>>(x1, a1_rows, a1_cols, a1_vals, out1, N_EDGES);
        spmm_atomic_kernel<<<blocks, 256, 0, stream>>>(x2, a2_rows, a2_cols, a2_vals, out2, N_EDGES);
        return;
    }

    hipMemsetAsync(gcur, 0, 2 * NBUCK * sizeof(int), stream);

    bin_kernel<<<2 * (N_EDGES / EPB), 1024, 0, stream>>>(
        x1, x2, xh,
        a1_rows, a1_cols, a1_vals, a2_rows, a2_cols, a2_vals, gcur, perm);

    spmm_kernel<<<2 * NBUCK, 1024, 0, stream>>>(gcur, perm, xh, out);
}

// Round 2
// 162.772 us; speedup vs baseline: 1.1563x; 1.1563x over previous
//
#include <hip/hip_runtime.h>
#include <hip/hip_bf16.h>

#define N_NODES 65536
#define D_FEAT  64
#define N_EDGES 1048576
#define NBUCK   512          // buckets per matrix; bucket = row >> 7
#define ROWS_PB 128
#define BCAP    2560         // mean 2048, +11 sigma headroom
#define EPB     8192         // edges per bin block
#define XH_ELEMS ((size_t)N_NODES * D_FEAT)   // 4,194,304 elems per matrix

// ---------------- bf16 helpers (round-to-nearest-even) ----------------
static __device__ __forceinline__ unsigned short f2bf(float f) {
    unsigned b = __float_as_uint(f);
    return (unsigned short)((b + 0x7fffu + ((b >> 16) & 1u)) >> 16);
}
static __device__ __forceinline__ float bf2f(unsigned short u) {
    return __uint_as_float(((unsigned)u) << 16);
}

// Wave64 inclusive scan via shfl_up (no barriers inside a wave).
static __device__ __forceinline__ int wave_incl_scan(int v, int lane) {
    #pragma unroll
    for (int d = 1; d < 64; d <<= 1) {
        int t = __shfl_up(v, d, 64);
        if (lane >= d) v += t;
    }
    return v;
}

// ---------------- bin (+ fused fp32->bf16 cvt): LDS counting sort -------
// 256 blocks (128/matrix) x 1024 threads x 8 edges. Each block also
// converts 8192 float4s of x1/x2 to bf16 (replaces the old cvt_kernel).
// Scan over 512 bins is shfl-based: 2 barriers instead of 18.
__global__ __launch_bounds__(1024) void bin_kernel(
    const float* __restrict__ x1, const float* __restrict__ x2,
    unsigned short* __restrict__ xh,
    const int* __restrict__ r1, const int* __restrict__ c1, const float* __restrict__ v1,
    const int* __restrict__ r2, const int* __restrict__ c2, const float* __restrict__ v2,
    int*   __restrict__ gcursor,       // [2*NBUCK], zeroed
    uint2* __restrict__ perm)          // [2*NBUCK*BCAP]
{
    __shared__ uint2 ent[EPB];                 // 64 KB
    __shared__ unsigned short binof[EPB];      // 16 KB
    __shared__ int hist[NBUCK];
    __shared__ int offs[NBUCK];
    __shared__ int cur[NBUCK];
    __shared__ int gbase[NBUCK];
    __shared__ int wsum[8];

    const int tid  = threadIdx.x;
    const int lane = tid & 63;
    const int wv   = tid >> 6;
    const int mat  = blockIdx.x >> 7;          // 128 blocks per matrix
    const int lb   = blockIdx.x & 127;
    const int*   rows = mat ? r2 : r1;
    const int*   cols = mat ? c2 : c1;
    const float* vals = mat ? v2 : v1;
    uint2* pm = perm + (size_t)mat * NBUCK * BCAP;

    for (int i = tid; i < NBUCK; i += 1024) hist[i] = 0;

    // Issue edge loads early; their latency hides under the cvt work.
    const int base_e = lb * EPB;
    int r[8], c[8];
    float v[8];
    *(int4*)&r[0]   = ((const int4*)(rows + base_e))[tid * 2];
    *(int4*)&r[4]   = ((const int4*)(rows + base_e))[tid * 2 + 1];
    *(int4*)&c[0]   = ((const int4*)(cols + base_e))[tid * 2];
    *(int4*)&c[4]   = ((const int4*)(cols + base_e))[tid * 2 + 1];
    *(float4*)&v[0] = ((const float4*)(vals + base_e))[tid * 2];
    *(float4*)&v[4] = ((const float4*)(vals + base_e))[tid * 2 + 1];

    // Fused cvt: 256 blocks x 8192 float4 = 2,097,152 float4 (both matrices).
    {
        const size_t half  = XH_ELEMS / 4;                 // float4s per matrix
        const size_t cbase = (size_t)blockIdx.x * 8192;
        #pragma unroll
        for (int k = 0; k < 8; ++k) {
            size_t i = cbase + (size_t)k * 1024 + tid;
            float4 f = (i < half) ? ((const float4*)x1)[i]
                                  : ((const float4*)x2)[i - half];
            ushort4 o;
            o.x = f2bf(f.x); o.y = f2bf(f.y); o.z = f2bf(f.z); o.w = f2bf(f.w);
            ((ushort4*)xh)[i] = o;
        }
    }

    __syncthreads();
    #pragma unroll
    for (int k = 0; k < 8; ++k) atomicAdd(&hist[r[k] >> 7], 1);
    __syncthreads();

    // Shfl-based exclusive scan over 512 bins (waves 0..7).
    int my = 0, incl = 0;
    if (wv < 8) {
        my   = hist[tid];
        incl = wave_incl_scan(my, lane);
        if (lane == 63) wsum[wv] = incl;
    }
    __syncthreads();
    if (wv < 8) {
        int add = 0;
        #pragma unroll
        for (int w = 0; w < 8; ++w) if (w < wv) add += wsum[w];
        const int excl = incl - my + add;
        offs[tid] = excl;
        cur[tid]  = excl;
        gbase[tid] = atomicAdd(&gcursor[mat * NBUCK + tid], my);   // reserve run
    }
    __syncthreads();

    // Scatter into LDS sorted-by-bucket order.
    #pragma unroll
    for (int k = 0; k < 8; ++k) {
        const int b = r[k] >> 7;
        const int pos = atomicAdd(&cur[b], 1);
        uint2 e;
        e.x = __float_as_uint(v[k]);
        e.y = ((unsigned)c[k] << 7) | ((unsigned)r[k] & 127u);
        ent[pos]   = e;
        binof[pos] = (unsigned short)b;
    }
    __syncthreads();

    // Burst write: consecutive i -> consecutive perm addresses within a run.
    for (int i = tid; i < EPB; i += 1024) {
        const int b   = binof[i];
        const int idx = gbase[b] + (i - offs[b]);
        if (idx < BCAP) pm[(size_t)b * BCAP + idx] = ent[i];
    }
}

// ---------------- fused in-LDS sort + CSR SpMM ----------------
// Proven 16-lane/ushort4 gather geometry (round-0: 62 us) + a row-PAIR
// phase ladder that keeps >=4 gathers in flight for short rows too:
//   P1 dual 2-deep (MLP4) while both rows have >=8 edges
//   P2 per-row 4-deep (MLP4) for a leftover long row
//   P3 dual singles (MLP2), P4 per-row singles + masked tail (MLP1)
__global__ __launch_bounds__(1024, 8) void spmm_kernel(
    const int*            __restrict__ gcursor,
    const uint2*          __restrict__ perm,
    const unsigned short* __restrict__ xh,
    float*                __restrict__ out)
{
    __shared__ uint2 ent[BCAP];            // 20 KB
    __shared__ int   hist[ROWS_PB];
    __shared__ int   offs[ROWS_PB + 1];
    __shared__ int   cur[ROWS_PB];
    __shared__ int   wscr[2];

    const int gb   = blockIdx.x;
    const int mat  = gb >> 9;
    const int b    = gb & 511;
    const int tid  = threadIdx.x;
    const int lane = tid & 63;
    const int wave = tid >> 6;

    const uint2* pbase = perm + ((size_t)mat * NBUCK + b) * BCAP;
    const unsigned short* xm = xh + (size_t)mat * XH_ELEMS;
    float* ob = out + (size_t)mat * XH_ELEMS + (size_t)b * ROWS_PB * D_FEAT;

    const int cnt = min(gcursor[mat * NBUCK + b], BCAP);

    if (tid < ROWS_PB) hist[tid] = 0;
    __syncthreads();

    uint2 mine[3];
    int nm = 0;
    for (int i = tid; i < cnt; i += 1024) {
        uint2 e = pbase[i];
        mine[nm++] = e;
        atomicAdd(&hist[e.y & (ROWS_PB - 1)], 1);
    }
    __syncthreads();

    // Shfl-based exclusive scan over 128 row-bins (waves 0..1).
    int my = 0, incl = 0;
    if (wave < 2) {
        my   = hist[tid];
        incl = wave_incl_scan(my, lane);
        if (lane == 63) wscr[wave] = incl;
    }
    __syncthreads();
    if (wave < 2) {
        const int excl = incl - my + (wave == 1 ? wscr[0] : 0);
        offs[tid] = excl;
        cur[tid]  = excl;
    }
    if (tid == 0) offs[ROWS_PB] = cnt;
    __syncthreads();

    for (int k = 0; k < nm; ++k) {
        int rr  = mine[k].y & (ROWS_PB - 1);
        int pos = atomicAdd(&cur[rr], 1);
        ent[pos] = mine[k];
    }
    __syncthreads();

    const int sub = lane >> 4;        // which of 4 edges in the group
    const int fl  = lane & 15;        // feature quad index

#define GB(ACC, EE) {                                                        \
        uint2 en = ent[(EE) + sub];                                          \
        float vv = __uint_as_float(en.x);                                    \
        ushort4 q = *(const ushort4*)(xm + (((size_t)(en.y >> 7)) << 6)      \
                                         + (fl << 2));                       \
        ACC.x = fmaf(vv, bf2f(q.x), ACC.x);                                  \
        ACC.y = fmaf(vv, bf2f(q.y), ACC.y);                                  \
        ACC.z = fmaf(vv, bf2f(q.z), ACC.z);                                  \
        ACC.w = fmaf(vv, bf2f(q.w), ACC.w); }

#define GM(ACC, EE, END) {                                                   \
        const int idx = (EE) + sub;                                          \
        const bool ok = idx < (END);                                         \
        uint2 en = ent[ok ? idx : (END) - 1];                                \
        float vv = ok ? __uint_as_float(en.x) : 0.f;                         \
        ushort4 q = *(const ushort4*)(xm + (((size_t)(en.y >> 7)) << 6)      \
                                         + (fl << 2));                       \
        ACC.x = fmaf(vv, bf2f(q.x), ACC.x);                                  \
        ACC.y = fmaf(vv, bf2f(q.y), ACC.y);                                  \
        ACC.z = fmaf(vv, bf2f(q.z), ACC.z);                                  \
        ACC.w = fmaf(vv, bf2f(q.w), ACC.w); }

    for (int rp = 0; rp < 8; rp += 2) {
        const int rA = wave * 8 + rp;
        const int rB = rA + 1;
        int eA = offs[rA]; const int endA = offs[rA + 1];
        int eB = endA;     const int endB = offs[rB + 1];

        float4 a  = make_float4(0.f, 0.f, 0.f, 0.f);
        float4 bb = make_float4(0.f, 0.f, 0.f, 0.f);

        // P1: dual 2-deep — 4 gathers in flight while both rows have work.
        while (eA + 8 <= endA && eB + 8 <= endB) {
            GB(a, eA) GB(a, eA + 4) GB(bb, eB) GB(bb, eB + 4)
            eA += 8; eB += 8;
        }
        // P2: leftover long row at 4-deep.
        while (eA + 16 <= endA) {
            GB(a, eA) GB(a, eA + 4) GB(a, eA + 8) GB(a, eA + 12)
            eA += 16;
        }
        while (eB + 16 <= endB) {
            GB(bb, eB) GB(bb, eB + 4) GB(bb, eB + 8) GB(bb, eB + 12)
            eB += 16;
        }
        // P3: dual singles (MLP2).
        while (eA + 4 <= endA && eB + 4 <= endB) {
            GB(a, eA) GB(bb, eB)
            eA += 4; eB += 4;
        }
        // P4: per-row singles + masked tails.
        while (eA + 4 <= endA) { GB(a, eA)  eA += 4; }
        while (eB + 4 <= endB) { GB(bb, eB) eB += 4; }
        if (eA < endA) GM(a, eA, endA)
        if (eB < endB) GM(bb, eB, endB)

        a.x += __shfl_xor(a.x, 16); a.y += __shfl_xor(a.y, 16);
        a.z += __shfl_xor(a.z, 16); a.w += __shfl_xor(a.w, 16);
        a.x += __shfl_xor(a.x, 32); a.y += __shfl_xor(a.y, 32);
        a.z += __shfl_xor(a.z, 32); a.w += __shfl_xor(a.w, 32);
        bb.x += __shfl_xor(bb.x, 16); bb.y += __shfl_xor(bb.y, 16);
        bb.z += __shfl_xor(bb.z, 16); bb.w += __shfl_xor(bb.w, 16);
        bb.x += __shfl_xor(bb.x, 32); bb.y += __shfl_xor(bb.y, 32);
        bb.z += __shfl_xor(bb.z, 32); bb.w += __shfl_xor(bb.w, 32);

        if (lane < 16) {
            *(float4*)(ob + rA * D_FEAT + (fl << 2)) = a;    // 256B/row store
            *(float4*)(ob + rB * D_FEAT + (fl << 2)) = bb;
        }
    }
#undef GB
#undef GM
}

// ---------------- Bottom fallback: atomic kernel ----------------
__global__ __launch_bounds__(256) void spmm_atomic_kernel(
    const float* __restrict__ x,
    const int*   __restrict__ rows,
    const int*   __restrict__ cols,
    const float* __restrict__ vals,
    float*       __restrict__ out,
    int n_edges)
{
    const int gid  = blockIdx.x * blockDim.x + threadIdx.x;
    const int edge = gid >> 6;
    const int lane = threadIdx.x & 63;
    if (edge >= n_edges) return;
    const int   r = rows[edge];
    const int   c = cols[edge];
    const float v = vals[edge];
    atomicAdd(&out[(size_t)r * D_FEAT + lane], v * x[(size_t)c * D_FEAT + lane]);
}

extern "C" void kernel_launch(void* const* d_in, const int* in_sizes, int n_in,
                              void* d_out, int out_size, void* d_ws, size_t ws_size,
                              hipStream_t stream) {
    const float* x1      = (const float*)d_in[0];
    const float* x2      = (const float*)d_in[1];
    const int*   a1_rows = (const int*)  d_in[2];
    const int*   a1_cols = (const int*)  d_in[3];
    const float* a1_vals = (const float*)d_in[4];
    const int*   a2_rows = (const int*)  d_in[5];
    const int*   a2_cols = (const int*)  d_in[6];
    const float* a2_vals = (const float*)d_in[7];

    float* out  = (float*)d_out;
    float* out1 = out;
    float* out2 = out + XH_ELEMS;

    // Workspace: gcursor[1024] | perm[1024*BCAP] | xh[2*XH_ELEMS] bf16
    int*   gcur = (int*)d_ws;
    uint2* perm = (uint2*)(gcur + 2 * NBUCK);
    unsigned short* xh = (unsigned short*)(perm + (size_t)2 * NBUCK * BCAP);

    const size_t needed = 2 * NBUCK * sizeof(int)
                        + (size_t)2 * NBUCK * BCAP * sizeof(uint2)
                        + (size_t)2 * XH_ELEMS * sizeof(short);    // ~37.8 MB

    if (ws_size < needed) {
        hipMemsetAsync(d_out, 0, (size_t)out_size * sizeof(float), stream);
        const int blocks = (N_EDGES * 64 + 255) / 256;
        spmm_atomic_kernel<<<blocks, 256, 0, stream>>>(x1, a1_rows, a1_cols, a1_vals, out1, N_EDGES);
        spmm_atomic_kernel<<<blocks, 256, 0, stream>>>(x2, a2_rows, a2_cols, a2_vals, out2, N_EDGES);
        return;
    }

    hipMemsetAsync(gcur, 0, 2 * NBUCK * sizeof(int), stream);

    bin_kernel<<<2 * (N_EDGES / EPB), 1024, 0, stream>>>(
        x1, x2, xh,
        a1_rows, a1_cols, a1_vals, a2_rows, a2_cols, a2_vals, gcur, perm);

    spmm_kernel<<<2 * NBUCK, 1024, 0, stream>>>(gcur, perm, xh, out);
}